// Round 1
// baseline (265.881 us; speedup 1.0000x reference)
//
#include <hip/hip_runtime.h>
#include <hip/hip_bf16.h>

#define C_CH 512
#define HW 16384
#define NB 8
#define TILE 128
#define BK 64
#define NTB 4            // C_CH / TILE
#define NTILES 10        // upper-triangular tiles: NTB*(NTB+1)/2
#define KSPLIT 8
#define KCHUNK (HW / KSPLIT)   // 2048
#define KSTEPS (KCHUNK / BK)   // 32
#define NGRAM 16
#define CC (C_CH * C_CH)
#define LOSS_BLOCKS 1024

typedef float f32x4 __attribute__((ext_vector_type(4)));
typedef float f32x8 __attribute__((ext_vector_type(8)));
typedef __bf16 bf16x8 __attribute__((ext_vector_type(8)));

// Gram SYRK: one (gram g, triangular tile t, k-slice ks) per block.
// 4 waves, each computes a 64x64 sub-tile as 4x4 MFMA 16x16x32 fragments.
__global__ __launch_bounds__(256) void gram_kernel(const float* __restrict__ det,
                                                   const float* __restrict__ sr,
                                                   float* __restrict__ gram) {
    const int tid = threadIdx.x;
    int bid = blockIdx.x;
    const int ks = bid & (KSPLIT - 1);
    bid >>= 3;
    const int t = bid % NTILES;
    const int g = bid / NTILES;          // 0..15: g<8 det batch g, g>=8 sr batch g-8
    const int tensor = g >> 3, b = g & 7;

    // triangular tile decode: (ti, tj) with tj >= ti
    int ti = 0, tt = t;
    while (tt >= NTB - ti) { tt -= NTB - ti; ++ti; }
    const int tj = ti + tt;
    const bool diag = (ti == tj);

    const float* F = (tensor ? sr : det) + (size_t)b * C_CH * HW;
    const int k0 = ks * KCHUNK;
    const float* Abase = F + (size_t)(ti * TILE) * HW + k0;
    const float* Bbase = F + (size_t)(tj * TILE) * HW + k0;

    __shared__ bf16x8 As8[TILE * BK / 8];   // 16 KiB
    __shared__ bf16x8 Bs8[TILE * BK / 8];   // 16 KiB
    __bf16* As = (__bf16*)As8;
    __bf16* Bs = (__bf16*)Bs8;

    const int lane = tid & 63;
    const int w = tid >> 6;
    const int wr = w >> 1, wc = w & 1;      // 2x2 waves over the 128x128 tile

    f32x4 acc[4][4] = {};

    for (int kt = 0; kt < KSTEPS; ++kt) {
        const int koff = kt * BK;
        __syncthreads();   // previous iteration's LDS reads are done
        // stage A panel: 128 rows x 64 k, fp32 -> bf16, XOR-swizzled chunks
        #pragma unroll
        for (int q = 0; q < 4; ++q) {
            int c = q * 256 + tid;          // flat chunk id: 128 rows x 8 chunks
            int row = c >> 3, ch = c & 7;
            f32x8 v = *(const f32x8*)(Abase + (size_t)row * HW + koff + ch * 8);
            bf16x8 h;
            #pragma unroll
            for (int i = 0; i < 8; ++i) h[i] = (__bf16)v[i];
            *(bf16x8*)(As + row * BK + ((ch ^ (row & 7)) << 3)) = h;
        }
        if (!diag) {
            #pragma unroll
            for (int q = 0; q < 4; ++q) {
                int c = q * 256 + tid;
                int row = c >> 3, ch = c & 7;
                f32x8 v = *(const f32x8*)(Bbase + (size_t)row * HW + koff + ch * 8);
                bf16x8 h;
                #pragma unroll
                for (int i = 0; i < 8; ++i) h[i] = (__bf16)v[i];
                *(bf16x8*)(Bs + row * BK + ((ch ^ (row & 7)) << 3)) = h;
            }
        }
        __syncthreads();
        const __bf16* Bsrc = diag ? As : Bs;   // diag tile: B-frags == A-frags layout
        #pragma unroll
        for (int ksub = 0; ksub < 2; ++ksub) {
            const int kchunk = ksub * 4 + (lane >> 4);
            bf16x8 af[4], bfr[4];
            #pragma unroll
            for (int m = 0; m < 4; ++m) {
                int row = wr * 64 + m * 16 + (lane & 15);
                af[m] = *(const bf16x8*)(As + row * BK + ((kchunk ^ (row & 7)) << 3));
            }
            #pragma unroll
            for (int n = 0; n < 4; ++n) {
                int row = wc * 64 + n * 16 + (lane & 15);
                bfr[n] = *(const bf16x8*)(Bsrc + row * BK + ((kchunk ^ (row & 7)) << 3));
            }
            #pragma unroll
            for (int m = 0; m < 4; ++m)
                #pragma unroll
                for (int n = 0; n < 4; ++n)
                    acc[m][n] = __builtin_amdgcn_mfma_f32_16x16x32_bf16(af[m], bfr[n], acc[m][n], 0, 0, 0);
        }
    }

    // epilogue: accumulate K-split partials. C/D layout: col=lane&15, row=(lane>>4)*4+j
    float* gout = gram + (size_t)g * CC;
    const int rbase = ti * TILE + wr * 64 + ((lane >> 4) << 2);
    const int cbase = tj * TILE + wc * 64 + (lane & 15);
    #pragma unroll
    for (int m = 0; m < 4; ++m)
        #pragma unroll
        for (int n = 0; n < 4; ++n)
            #pragma unroll
            for (int j = 0; j < 4; ++j)
                atomicAdd(&gout[(size_t)(rbase + m * 16 + j) * C_CH + cbase + n * 16], acc[m][n][j]);
}

__global__ void norm_kernel(const float* __restrict__ gram, float* __restrict__ invn) {
    const int g = blockIdx.x, c = threadIdx.x;
    float v = gram[(size_t)g * CC + (size_t)c * C_CH + c];
    invn[g * C_CH + c] = 1.0f / sqrtf(v);
}

__global__ __launch_bounds__(256) void loss_kernel(const float* __restrict__ gram,
                                                   const float* __restrict__ invn,
                                                   float* __restrict__ partials) {
    const int tid = threadIdx.x;
    float s = 0.f;
    for (int idx = blockIdx.x * 256 + tid; idx < NB * CC; idx += LOSS_BLOCKS * 256) {
        int b = idx >> 18;
        int c = (idx >> 9) & 511;
        int d = idx & 511;
        int cc = c, dd = d;
        if ((dd >> 7) < (cc >> 7)) { int tmp = cc; cc = dd; dd = tmp; }  // only upper tiles stored
        float gd = gram[(size_t)b * CC + (size_t)cc * C_CH + dd];
        float gs = gram[(size_t)(8 + b) * CC + (size_t)cc * C_CH + dd];
        float sd = gd * invn[b * C_CH + c] * invn[b * C_CH + d];
        float ss = gs * invn[(8 + b) * C_CH + c] * invn[(8 + b) * C_CH + d];
        float diff = sd - ss;
        s += diff * diff;
    }
    #pragma unroll
    for (int off = 32; off > 0; off >>= 1) s += __shfl_down(s, off, 64);
    __shared__ float red[4];
    if ((tid & 63) == 0) red[tid >> 6] = s;
    __syncthreads();
    if (tid == 0) partials[blockIdx.x] = red[0] + red[1] + red[2] + red[3];
}

__global__ void final_kernel(const float* __restrict__ partials, float* __restrict__ out) {
    const int tid = threadIdx.x;  // 256
    float s = 0.f;
    for (int i = tid; i < LOSS_BLOCKS; i += 256) s += partials[i];
    #pragma unroll
    for (int off = 32; off > 0; off >>= 1) s += __shfl_down(s, off, 64);
    __shared__ float red[4];
    if ((tid & 63) == 0) red[tid >> 6] = s;
    __syncthreads();
    if (tid == 0) out[0] = (red[0] + red[1] + red[2] + red[3]) * (1.0f / (float)(NB * (size_t)CC));
}

extern "C" void kernel_launch(void* const* d_in, const int* in_sizes, int n_in,
                              void* d_out, int out_size, void* d_ws, size_t ws_size,
                              hipStream_t stream) {
    const float* det = (const float*)d_in[0];
    const float* sr  = (const float*)d_in[1];
    float* gram     = (float*)d_ws;                       // 16 * 512 * 512 f32 = 16.78 MB
    float* invn     = gram + (size_t)NGRAM * CC;          // 16 * 512 f32
    float* partials = invn + NGRAM * C_CH;                // 1024 f32
    float* out      = (float*)d_out;

    hipMemsetAsync(gram, 0, (size_t)NGRAM * CC * sizeof(float), stream);
    gram_kernel<<<NGRAM * NTILES * KSPLIT, 256, 0, stream>>>(det, sr, gram);
    norm_kernel<<<NGRAM, C_CH, 0, stream>>>(gram, invn);
    loss_kernel<<<LOSS_BLOCKS, 256, 0, stream>>>(gram, invn, partials);
    final_kernel<<<1, 256, 0, stream>>>(partials, out);
}